// Round 4
// baseline (3896.550 us; speedup 1.0000x reference)
//
#include <hip/hip_runtime.h>
#include <hip/hip_fp16.h>

#define B_  32
#define T_  2048
#define I_  256
#define H_  128

typedef _Float16 f16;
typedef _Float16 f16x4 __attribute__((ext_vector_type(4)));
typedef _Float16 f16x8 __attribute__((ext_vector_type(8)));
typedef float    f32x4 __attribute__((ext_vector_type(4)));

// sigmoid(x) = 1/(1+2^(-x*log2e));  tanh(x) = 2/(1+2^(-2x*log2e)) - 1
static __device__ __forceinline__ float fast_sig(float x) {
  float e = __builtin_amdgcn_exp2f(-1.44269504089f * x);
  return __builtin_amdgcn_rcpf(1.0f + e);
}
static __device__ __forceinline__ float fast_tanh(float x) {
  float e = __builtin_amdgcn_exp2f(-2.88539008178f * x);
  return 2.0f * __builtin_amdgcn_rcpf(1.0f + e) - 1.0f;
}

// LDS-only barrier: do NOT drain vmcnt -- global prefetch loads and out[]
// stores float across rounds.  sched_barrier(0) fences per rule #18.
#define BARRIER_LDS()                                   \
  __builtin_amdgcn_sched_barrier(0);                    \
  asm volatile("s_waitcnt lgkmcnt(0)" ::: "memory");    \
  __builtin_amdgcn_s_barrier();                         \
  __builtin_amdgcn_sched_barrier(0)

#define MFMA16(a, b, c) __builtin_amdgcn_mfma_f32_16x16x32_f16((a), (b), (c), 0, 0, 0)

// ---------------------------------------------------------------------------
// Kernel 1: xg[m][n] = sum_k x[m][k] * W'[n][k] + b_ih[n] + b_hh[n]
//   (unchanged -- ~80 us, not the bottleneck)
// ---------------------------------------------------------------------------
__global__ __launch_bounds__(256) void xg_gemm(
    const float* __restrict__ x,
    const float* __restrict__ Wf, const float* __restrict__ Wb,
    const float* __restrict__ bf_ih, const float* __restrict__ bf_hh,
    const float* __restrict__ bb_ih, const float* __restrict__ bb_hh,
    f16* __restrict__ xg)
{
  __shared__ f16 xs[128][136];   // +8 f16 pad
  __shared__ f16 wt[128][136];

  const int tid = threadIdx.x;
  const int m0  = blockIdx.y * 128;
  const int n0  = blockIdx.x * 128;

  const float* Wsrc; const float* bih; const float* bhh; int nb;
  if (n0 < 512) { Wsrc = Wf; bih = bf_ih; bhh = bf_hh; nb = n0; }
  else          { Wsrc = Wb; bih = bb_ih; bhh = bb_hh; nb = n0 - 512; }

  const int w  = tid >> 6;
  const int l  = tid & 63;
  const int lr = l & 15;
  const int lk = (l >> 4) * 8;

  f32x4 acc[2][8] = {};

  #pragma unroll
  for (int kh = 0; kh < 2; ++kh) {
    #pragma unroll
    for (int it = 0; it < 16; ++it) {
      int idx = it * 256 + tid;
      int row = idx >> 5, c4 = idx & 31;
      float4 v = *(const float4*)&x[(size_t)(m0 + row) * I_ + kh * 128 + c4 * 4];
      f16x4 h4 = { (f16)v.x, (f16)v.y, (f16)v.z, (f16)v.w };
      *(f16x4*)&xs[row][c4 * 4] = h4;
    }
    #pragma unroll
    for (int it = 0; it < 16; ++it) {
      int idx = it * 256 + tid;
      int row = idx >> 5, c4 = idx & 31;
      float4 v = *(const float4*)&Wsrc[(size_t)(nb + row) * I_ + kh * 128 + c4 * 4];
      f16x4 h4 = { (f16)v.x, (f16)v.y, (f16)v.z, (f16)v.w };
      *(f16x4*)&wt[row][c4 * 4] = h4;
    }
    __syncthreads();

    #pragma unroll
    for (int ks = 0; ks < 4; ++ks) {
      int kk = ks * 32 + lk;
      f16x8 a0 = *(const f16x8*)&xs[w * 32 + lr][kk];
      f16x8 a1 = *(const f16x8*)&xs[w * 32 + 16 + lr][kk];
      #pragma unroll
      for (int nt = 0; nt < 8; ++nt) {
        f16x8 bf = *(const f16x8*)&wt[nt * 16 + lr][kk];
        acc[0][nt] = MFMA16(a0, bf, acc[0][nt]);
        acc[1][nt] = MFMA16(a1, bf, acc[1][nt]);
      }
    }
    __syncthreads();
  }

  #pragma unroll
  for (int mt = 0; mt < 2; ++mt) {
    #pragma unroll
    for (int nt = 0; nt < 8; ++nt) {
      int nloc = nt * 16 + lr;
      float bias = bih[nb + nloc] + bhh[nb + nloc];
      #pragma unroll
      for (int r = 0; r < 4; ++r) {
        int m = m0 + w * 32 + mt * 16 + (l >> 4) * 4 + r;
        xg[(size_t)m * 1024 + n0 + nloc] = (f16)(acc[mt][nt][r] + bias);
      }
    }
  }
}

// ---------------------------------------------------------------------------
// Kernel 2: recurrence via MFMA, C=4 chains per WG (latency amortization).
//   16 WGs x 512 thr (8 waves).  WG wg: dir = wg>>3, batches b0..b0+3 where
//   b0 = (wg&7)*4.  All chains share dir -> one 64-VGPR W_hh fragment set.
//   Per round (one time-step for all 4 chains): 4x{4 ds_read_b128 + 16 MFMA}
//   per wave, 4 nonlin blocks, ONE LDS-only barrier.  Independent chains
//   overlap each other's latencies (LDS round-trip, MFMA dep chain, trans).
//   Wave w owns N-tiles {w,8+w,16+w,24+w} = gates i,f,g,o of units w*16+c;
//   gates land lane-local in lanes 0..15 reg 0 (m89 layout, verified R3).
// ---------------------------------------------------------------------------
__global__ __launch_bounds__(512, 1) void birnn_rec(
    const f16* __restrict__ xg,
    const float* __restrict__ Wfhh, const float* __restrict__ Wbhh,
    const int* __restrict__ lengths,
    float* __restrict__ out)
{
  const int tid  = threadIdx.x;
  const int wave = tid >> 6;
  const int l    = tid & 63;
  const int c    = l & 15;
  const int kgrp = l >> 4;
  const int wg   = blockIdx.x;      // 0..15
  const int dir  = wg >> 3;
  const int b0   = (wg & 7) * 4;
  const float* Whh = dir ? Wbhh : Wfhh;

  int Ls[4];
  #pragma unroll
  for (int ch = 0; ch < 4; ++ch) Ls[ch] = lengths[b0 + ch];

  // B-fragments: bfrag[q][ks] = W_hh[n = q*128 + wave*16 + c][ks*32 + kgrp*8 ..+8]
  f16x8 bfrag[4][4];
  #pragma unroll
  for (int q = 0; q < 4; ++q) {
    int n = q * 128 + wave * 16 + c;
    #pragma unroll
    for (int ks = 0; ks < 4; ++ks) {
      int k0 = ks * 32 + kgrp * 8;
      float4 va = *(const float4*)&Whh[(size_t)n * H_ + k0];
      float4 vb = *(const float4*)&Whh[(size_t)n * H_ + k0 + 4];
      bfrag[q][ks] = (f16x8){ (f16)va.x, (f16)va.y, (f16)va.z, (f16)va.w,
                              (f16)vb.x, (f16)vb.y, (f16)vb.z, (f16)vb.w };
    }
  }

  __shared__ __align__(16) f16 hbuf[4][2][128];
  if (tid < 128) {
    #pragma unroll
    for (int ch = 0; ch < 4; ++ch) hbuf[ch][0][tid] = (f16)0.0f;
  }
  float cst[4] = { 0.f, 0.f, 0.f, 0.f };
  __syncthreads();

  auto rowof = [&](int ch, int t) -> size_t {
    int it = t;
    if (dir) it = (t < Ls[ch]) ? (Ls[ch] - 1 - t) : t;
    return ((size_t)((b0 + ch) * T_ + it)) * 1024 + (size_t)dir * 512;
  };
  const int goff = wave * 16 + c;
  const bool row0 = (l < 16);

  // depth-2 (in rounds) xg prefetch; [4][4] arrays fully unrolled -> registers
  f16 pa[4][4], pb[4][4];
  #pragma unroll
  for (int ch = 0; ch < 4; ++ch) {
    size_t r0 = rowof(ch, 0), r1 = rowof(ch, 1);
    #pragma unroll
    for (int q = 0; q < 4; ++q) {
      pa[ch][q] = xg[r0 + q * 128 + goff];
      pb[ch][q] = xg[r1 + q * 128 + goff];
    }
  }

#define ROUND(t, P, RB, WB)                                                   \
  {                                                                           \
    f32x4 Ai[4], Af[4], Ag[4], Ao[4];                                         \
    _Pragma("unroll")                                                         \
    for (int ch = 0; ch < 4; ++ch) {                                          \
      Ai[ch] = (f32x4){}; Af[ch] = (f32x4){};                                 \
      Ag[ch] = (f32x4){}; Ao[ch] = (f32x4){};                                 \
      Ai[ch][0] = row0 ? (float)P[ch][0] : 0.0f;                              \
      Af[ch][0] = row0 ? (float)P[ch][1] : 0.0f;                              \
      Ag[ch][0] = row0 ? (float)P[ch][2] : 0.0f;                              \
      Ao[ch][0] = row0 ? (float)P[ch][3] : 0.0f;                              \
    }                                                                         \
    if ((t) + 2 < T_) {                                                       \
      _Pragma("unroll")                                                       \
      for (int ch = 0; ch < 4; ++ch) {                                        \
        size_t r2 = rowof(ch, (t) + 2);                                       \
        P[ch][0] = xg[r2 + 0 * 128 + goff];                                   \
        P[ch][1] = xg[r2 + 1 * 128 + goff];                                   \
        P[ch][2] = xg[r2 + 2 * 128 + goff];                                   \
        P[ch][3] = xg[r2 + 3 * 128 + goff];                                   \
      }                                                                       \
    }                                                                         \
    _Pragma("unroll")                                                         \
    for (int ch = 0; ch < 4; ++ch) {                                          \
      const f16* hr = &hbuf[ch][RB][0];                                       \
      f16x8 af0 = *(const f16x8*)&hr[kgrp * 8];                               \
      f16x8 af1 = *(const f16x8*)&hr[32 + kgrp * 8];                          \
      f16x8 af2 = *(const f16x8*)&hr[64 + kgrp * 8];                          \
      f16x8 af3 = *(const f16x8*)&hr[96 + kgrp * 8];                          \
      Ai[ch] = MFMA16(af0, bfrag[0][0], Ai[ch]);                              \
      Af[ch] = MFMA16(af0, bfrag[1][0], Af[ch]);                              \
      Ag[ch] = MFMA16(af0, bfrag[2][0], Ag[ch]);                              \
      Ao[ch] = MFMA16(af0, bfrag[3][0], Ao[ch]);                              \
      Ai[ch] = MFMA16(af1, bfrag[0][1], Ai[ch]);                              \
      Af[ch] = MFMA16(af1, bfrag[1][1], Af[ch]);                              \
      Ag[ch] = MFMA16(af1, bfrag[2][1], Ag[ch]);                              \
      Ao[ch] = MFMA16(af1, bfrag[3][1], Ao[ch]);                              \
      Ai[ch] = MFMA16(af2, bfrag[0][2], Ai[ch]);                              \
      Af[ch] = MFMA16(af2, bfrag[1][2], Af[ch]);                              \
      Ag[ch] = MFMA16(af2, bfrag[2][2], Ag[ch]);                              \
      Ao[ch] = MFMA16(af2, bfrag[3][2], Ao[ch]);                              \
      Ai[ch] = MFMA16(af3, bfrag[0][3], Ai[ch]);                              \
      Af[ch] = MFMA16(af3, bfrag[1][3], Af[ch]);                              \
      Ag[ch] = MFMA16(af3, bfrag[2][3], Ag[ch]);                              \
      Ao[ch] = MFMA16(af3, bfrag[3][3], Ao[ch]);                              \
    }                                                                         \
    if (row0) {                                                               \
      _Pragma("unroll")                                                       \
      for (int ch = 0; ch < 4; ++ch) {                                        \
        float is = fast_sig(Ai[ch][0]);                                       \
        float fs = fast_sig(Af[ch][0]);                                       \
        float gt = fast_tanh(Ag[ch][0]);                                      \
        float os = fast_sig(Ao[ch][0]);                                       \
        cst[ch] = fs * cst[ch] + is * gt;                                     \
        float hval = os * fast_tanh(cst[ch]);                                 \
        hbuf[ch][WB][goff] = (f16)hval;                                       \
        out[((size_t)((b0 + ch) * T_ + (t))) * 256 + dir * 128 + goff] = hval;\
      }                                                                       \
    }                                                                         \
    BARRIER_LDS();                                                            \
  }

  for (int tt = 0; tt < T_; tt += 2) {
    ROUND(tt,     pa, 0, 1);
    ROUND(tt + 1, pb, 1, 0);
  }
#undef ROUND
}

// ---------------------------------------------------------------------------
extern "C" void kernel_launch(void* const* d_in, const int* in_sizes, int n_in,
                              void* d_out, int out_size, void* d_ws, size_t ws_size,
                              hipStream_t stream) {
  const float* x      = (const float*)d_in[0];
  const int*   lengths= (const int*)  d_in[1];
  const float* Wf_ih  = (const float*)d_in[2];
  const float* Wf_hh  = (const float*)d_in[3];
  const float* bf_ih  = (const float*)d_in[4];
  const float* bf_hh  = (const float*)d_in[5];
  const float* Wb_ih  = (const float*)d_in[6];
  const float* Wb_hh  = (const float*)d_in[7];
  const float* bb_ih  = (const float*)d_in[8];
  const float* bb_hh  = (const float*)d_in[9];
  float* out = (float*)d_out;
  f16*   xg  = (f16*)d_ws;   // needs B*T*1024*2 = 134,217,728 bytes

  (void)in_sizes; (void)n_in; (void)out_size; (void)ws_size;

  xg_gemm<<<dim3(8, 512), 256, 0, stream>>>(x, Wf_ih, Wb_ih,
                                            bf_ih, bf_hh, bb_ih, bb_hh, xg);
  birnn_rec<<<dim3(16), 512, 0, stream>>>(xg, Wf_hh, Wb_hh, lengths, out);
}

// Round 5
// 1347.036 us; speedup vs baseline: 2.8927x; 2.8927x over previous
//
#include <hip/hip_runtime.h>
#include <hip/hip_fp16.h>

#define B_  32
#define T_  2048
#define I_  256
#define H_  128

typedef _Float16 f16;
typedef _Float16 f16x2 __attribute__((ext_vector_type(2)));
typedef _Float16 f16x4 __attribute__((ext_vector_type(4)));
typedef _Float16 f16x8 __attribute__((ext_vector_type(8)));
typedef float    f32x4 __attribute__((ext_vector_type(4)));

#if __has_builtin(__builtin_amdgcn_fdot2)
#define FDOT2(a, b, c) __builtin_amdgcn_fdot2((a), (b), (c), false)
#else
static __device__ __forceinline__ float FDOT2(f16x2 a, f16x2 b, float c) {
  return c + (float)a[0] * (float)b[0] + (float)a[1] * (float)b[1];
}
#endif

static __device__ __forceinline__ f16x2 asf16x2(unsigned u) {
  return __builtin_bit_cast(f16x2, u);
}

// sigmoid(x) = 1/(1+2^(-x*log2e))
static __device__ __forceinline__ float fast_sig(float x) {
  float e = __builtin_amdgcn_exp2f(-1.44269504089f * x);
  return __builtin_amdgcn_rcpf(1.0f + e);
}
static __device__ __forceinline__ float fast_tanh(float x) {
  float e = __builtin_amdgcn_exp2f(-2.88539008178f * x);
  return 2.0f * __builtin_amdgcn_rcpf(1.0f + e) - 1.0f;
}

// LDS-only barrier: do NOT drain vmcnt -- global prefetch loads and out[]
// stores float across steps.  sched_barrier(0) fences per rule #18.
#define BARRIER_LDS()                                   \
  __builtin_amdgcn_sched_barrier(0);                    \
  asm volatile("s_waitcnt lgkmcnt(0)" ::: "memory");    \
  __builtin_amdgcn_s_barrier();                         \
  __builtin_amdgcn_sched_barrier(0)

#define MFMA16(a, b, c) __builtin_amdgcn_mfma_f32_16x16x32_f16((a), (b), (c), 0, 0, 0)

// ---------------------------------------------------------------------------
// Kernel 1: xg[m][n] = sum_k x[m][k] * W'[n][k] + b_ih[n] + b_hh[n]
//   (unchanged from R2 -- ~85 us, not the bottleneck)
// ---------------------------------------------------------------------------
__global__ __launch_bounds__(256) void xg_gemm(
    const float* __restrict__ x,
    const float* __restrict__ Wf, const float* __restrict__ Wb,
    const float* __restrict__ bf_ih, const float* __restrict__ bf_hh,
    const float* __restrict__ bb_ih, const float* __restrict__ bb_hh,
    f16* __restrict__ xg)
{
  __shared__ f16 xs[128][136];   // +8 f16 pad
  __shared__ f16 wt[128][136];

  const int tid = threadIdx.x;
  const int m0  = blockIdx.y * 128;
  const int n0  = blockIdx.x * 128;

  const float* Wsrc; const float* bih; const float* bhh; int nb;
  if (n0 < 512) { Wsrc = Wf; bih = bf_ih; bhh = bf_hh; nb = n0; }
  else          { Wsrc = Wb; bih = bb_ih; bhh = bb_hh; nb = n0 - 512; }

  const int w  = tid >> 6;
  const int l  = tid & 63;
  const int lr = l & 15;
  const int lk = (l >> 4) * 8;

  f32x4 acc[2][8] = {};

  #pragma unroll
  for (int kh = 0; kh < 2; ++kh) {
    #pragma unroll
    for (int it = 0; it < 16; ++it) {
      int idx = it * 256 + tid;
      int row = idx >> 5, c4 = idx & 31;
      float4 v = *(const float4*)&x[(size_t)(m0 + row) * I_ + kh * 128 + c4 * 4];
      f16x4 h4 = { (f16)v.x, (f16)v.y, (f16)v.z, (f16)v.w };
      *(f16x4*)&xs[row][c4 * 4] = h4;
    }
    #pragma unroll
    for (int it = 0; it < 16; ++it) {
      int idx = it * 256 + tid;
      int row = idx >> 5, c4 = idx & 31;
      float4 v = *(const float4*)&Wsrc[(size_t)(nb + row) * I_ + kh * 128 + c4 * 4];
      f16x4 h4 = { (f16)v.x, (f16)v.y, (f16)v.z, (f16)v.w };
      *(f16x4*)&wt[row][c4 * 4] = h4;
    }
    __syncthreads();

    #pragma unroll
    for (int ks = 0; ks < 4; ++ks) {
      int kk = ks * 32 + lk;
      f16x8 a0 = *(const f16x8*)&xs[w * 32 + lr][kk];
      f16x8 a1 = *(const f16x8*)&xs[w * 32 + 16 + lr][kk];
      #pragma unroll
      for (int nt = 0; nt < 8; ++nt) {
        f16x8 bf = *(const f16x8*)&wt[nt * 16 + lr][kk];
        acc[0][nt] = MFMA16(a0, bf, acc[0][nt]);
        acc[1][nt] = MFMA16(a1, bf, acc[1][nt]);
      }
    }
    __syncthreads();
  }

  #pragma unroll
  for (int mt = 0; mt < 2; ++mt) {
    #pragma unroll
    for (int nt = 0; nt < 8; ++nt) {
      int nloc = nt * 16 + lr;
      float bias = bih[nb + nloc] + bhh[nb + nloc];
      #pragma unroll
      for (int r = 0; r < 4; ++r) {
        int m = m0 + w * 32 + mt * 16 + (l >> 4) * 4 + r;
        xg[(size_t)m * 1024 + n0 + nloc] = (f16)(acc[mt][nt][r] + bias);
      }
    }
  }
}

// ---------------------------------------------------------------------------
// Kernel 2: recurrence, R2 VALU structure + in-wave gate exchange.
//   64 WGs x 256 thr (4 waves), 1 chain per WG.  Wave w, lane l:
//     unit u = w*32 + (l&31);  role = l>>5
//     role 0 lanes own gate rows {u, 256+u}      = (i_u, g_u)
//     role 1 lanes own gate rows {128+u, 384+u}  = (f_u, o_u)
//   (i,g)<->(f,o) exchange via __shfl_xor(.,32) -- same wave, NO barrier.
//   Both halves redundantly compute c,h (convergent); role-0 writes h.
//   ONE LDS-only barrier per step (double-buffered h broadcast buffer).
//   W_hh rows in 128 VGPRs as f16x2 words.
// ---------------------------------------------------------------------------
__global__ __launch_bounds__(256, 1) void birnn_rec(
    const f16* __restrict__ xg,
    const float* __restrict__ Wfhh, const float* __restrict__ Wbhh,
    const int* __restrict__ lengths,
    float* __restrict__ out)
{
  const int tid  = threadIdx.x;
  const int w    = tid >> 6;
  const int l    = tid & 63;
  const int role = l >> 5;                 // 0: (i,g)   1: (f,o)
  const int ul   = w * 32 + (l & 31);      // unit index
  const int dir  = blockIdx.x >> 5;
  const int b    = blockIdx.x & 31;
  const float* Whh = dir ? Wbhh : Wfhh;
  const int L    = lengths[b];

  const int rowA = role ? (128 + ul) : ul;   // i or f
  const int rowB = rowA + 256;               // g or o

  // W_hh rows rowA,rowB -> f16x2 register arrays (fully unrolled)
  unsigned w0[64], w1[64];
  #pragma unroll
  for (int j = 0; j < 32; ++j) {
    float4 v = *(const float4*)&Whh[(size_t)rowA * H_ + j * 4];
    w0[2 * j]     = __builtin_bit_cast(unsigned, (f16x2){ (f16)v.x, (f16)v.y });
    w0[2 * j + 1] = __builtin_bit_cast(unsigned, (f16x2){ (f16)v.z, (f16)v.w });
    float4 u = *(const float4*)&Whh[(size_t)rowB * H_ + j * 4];
    w1[2 * j]     = __builtin_bit_cast(unsigned, (f16x2){ (f16)u.x, (f16)u.y });
    w1[2 * j + 1] = __builtin_bit_cast(unsigned, (f16x2){ (f16)u.z, (f16)u.w });
  }

  __shared__ __align__(16) f16 hbuf[2][128];   // h broadcast, double-buffered
  if (tid < 128) hbuf[0][tid] = (f16)0.0f;
  float c = 0.0f;
  __syncthreads();

  auto rowof = [&](int t) -> size_t {
    int it = t;
    if (dir) it = (t < L) ? (L - 1 - t) : t;
    return ((size_t)(b * T_ + it)) * 1024 + (size_t)dir * 512;
  };

  // depth-2 xg prefetch (named slots)
  f16 pa0, pa1, pb0, pb1;
  { size_t r = rowof(0); pa0 = xg[r + rowA]; pa1 = xg[r + rowB]; }
  { size_t r = rowof(1); pb0 = xg[r + rowA]; pb1 = xg[r + rowB]; }

  // role-blend constants for the "B" gate: role0 -> tanh (2*sig(2x)-1),
  // role1 -> sig (sig(x)).
  const float bscale = role ? 1.0f : 2.0f;
  const float bmul   = role ? 1.0f : 2.0f;
  const float badd   = role ? 0.0f : -1.0f;

#define STEP(t, P0, P1, RB, WB)                                              \
  {                                                                          \
    float aA[4] = { (float)(P0), 0.f, 0.f, 0.f };                            \
    float aB[4] = { (float)(P1), 0.f, 0.f, 0.f };                            \
    if ((t) + 2 < T_) {                                                      \
      size_t r2 = rowof((t) + 2);                                            \
      (P0) = xg[r2 + rowA];                                                  \
      (P1) = xg[r2 + rowB];                                                  \
    }                                                                        \
    _Pragma("unroll")                                                        \
    for (int j4 = 0; j4 < 16; ++j4) {                                        \
      uint4 hv = *(const uint4*)&hbuf[RB][j4 * 8];                           \
      aA[0] = FDOT2(asf16x2(hv.x), asf16x2(w0[j4 * 4 + 0]), aA[0]);          \
      aB[0] = FDOT2(asf16x2(hv.x), asf16x2(w1[j4 * 4 + 0]), aB[0]);          \
      aA[1] = FDOT2(asf16x2(hv.y), asf16x2(w0[j4 * 4 + 1]), aA[1]);          \
      aB[1] = FDOT2(asf16x2(hv.y), asf16x2(w1[j4 * 4 + 1]), aB[1]);          \
      aA[2] = FDOT2(asf16x2(hv.z), asf16x2(w0[j4 * 4 + 2]), aA[2]);          \
      aB[2] = FDOT2(asf16x2(hv.z), asf16x2(w1[j4 * 4 + 2]), aB[2]);          \
      aA[3] = FDOT2(asf16x2(hv.w), asf16x2(w0[j4 * 4 + 3]), aA[3]);          \
      aB[3] = FDOT2(asf16x2(hv.w), asf16x2(w1[j4 * 4 + 3]), aB[3]);          \
    }                                                                        \
    float sumA = (aA[0] + aA[1]) + (aA[2] + aA[3]);                          \
    float sumB = (aB[0] + aB[1]) + (aB[2] + aB[3]);                          \
    /* sA: sig for both roles.  sB: role0 tanh = 2*sig(2x)-1, role1 sig. */  \
    float sA = fast_sig(sumA);                                               \
    float sB = fast_sig(bscale * sumB) * bmul + badd;                        \
    float pA = __shfl_xor(sA, 32, 64);                                       \
    float pB = __shfl_xor(sB, 32, 64);                                       \
    float is_ = role ? pA : sA;                                              \
    float gt_ = role ? pB : sB;                                              \
    float fs_ = role ? sA : pA;                                              \
    float os_ = role ? sB : pB;                                              \
    c = fs_ * c + is_ * gt_;                                                 \
    float hval = os_ * fast_tanh(c);                                         \
    if (!role) {                                                             \
      hbuf[WB][ul] = (f16)hval;                                              \
      out[((size_t)(b * T_ + (t))) * 256 + dir * 128 + ul] = hval;           \
    }                                                                        \
    BARRIER_LDS();                                                           \
  }

  for (int tt = 0; tt < T_; tt += 2) {
    STEP(tt,     pa0, pa1, 0, 1);
    STEP(tt + 1, pb0, pb1, 1, 0);
  }
#undef STEP
}

// ---------------------------------------------------------------------------
extern "C" void kernel_launch(void* const* d_in, const int* in_sizes, int n_in,
                              void* d_out, int out_size, void* d_ws, size_t ws_size,
                              hipStream_t stream) {
  const float* x      = (const float*)d_in[0];
  const int*   lengths= (const int*)  d_in[1];
  const float* Wf_ih  = (const float*)d_in[2];
  const float* Wf_hh  = (const float*)d_in[3];
  const float* bf_ih  = (const float*)d_in[4];
  const float* bf_hh  = (const float*)d_in[5];
  const float* Wb_ih  = (const float*)d_in[6];
  const float* Wb_hh  = (const float*)d_in[7];
  const float* bb_ih  = (const float*)d_in[8];
  const float* bb_hh  = (const float*)d_in[9];
  float* out = (float*)d_out;
  f16*   xg  = (f16*)d_ws;   // needs B*T*1024*2 = 134,217,728 bytes

  (void)in_sizes; (void)n_in; (void)out_size; (void)ws_size;

  xg_gemm<<<dim3(8, 512), 256, 0, stream>>>(x, Wf_ih, Wb_ih,
                                            bf_ih, bf_hh, bb_ih, bb_hh, xg);
  birnn_rec<<<dim3(64), 256, 0, stream>>>(xg, Wf_hh, Wb_hh, lengths, out);
}